// Round 4
// baseline (1065.863 us; speedup 1.0000x reference)
//
#include <hip/hip_runtime.h>

#define N_NODES 50000
#define N_EDGES 800000
// feats: 512 -> 512 -> 512 -> 256; K is always 512. Internal dtype: fp16.
// H (GEMM output / agg input) is CHUNK-BLOCKED: [chunk][node][32feats]; one
// chunk = 50000*64B = 3.2MB < 4MiB per-XCD L2; agg grid pins chunk->XCD via
// blockIdx.x (gridDim.x=8) so random gathers are L2-resident (proven: FETCH
// 425MB -> 56MB). v3 agg: node-slot layout (16 nodes/wave, 4 lanes x 16B per
// row, zero-shuffle epilogue) + degree-sorted node order (counting sort) to
// kill ragged-mask waste + per-wave LDS index slabs (no block barriers).

typedef __attribute__((ext_vector_type(8))) _Float16 half8;
typedef __attribute__((ext_vector_type(4))) float f32x4;
typedef __attribute__((ext_vector_type(4))) int i32x4;
typedef __attribute__((ext_vector_type(8))) unsigned short ushort8;

// ---------------- fp16 helpers ----------------
static __device__ __forceinline__ unsigned short f2h(float f) {
    _Float16 h = (_Float16)f;   // RNE
    return __builtin_bit_cast(unsigned short, h);
}
static __device__ __forceinline__ float h2f(unsigned short u) {
    return (float)__builtin_bit_cast(_Float16, u);
}

// async global->LDS, 16B per lane (wave-uniform LDS base + lane*16 layout)
static __device__ __forceinline__ void async16(unsigned short* lds, const unsigned short* g) {
    __builtin_amdgcn_global_load_lds(
        (const __attribute__((address_space(1))) void*)g,
        (__attribute__((address_space(3))) void*)lds, 16, 0, 0);
}

// ---------------- int degree histograms ----------------
__global__ void hist_kernel(const int* __restrict__ src, const int* __restrict__ dst,
                            int* __restrict__ outc, int* __restrict__ inc) {
    int i = blockIdx.x * blockDim.x + threadIdx.x;
    if (i < N_EDGES) {
        atomicAdd(&outc[src[i]], 1);
        atomicAdd(&inc[dst[i]], 1);
    }
}

__global__ void norm_kernel(const int* __restrict__ outc, const int* __restrict__ inc,
                            float* __restrict__ outn, float* __restrict__ inn) {
    int i = blockIdx.x * blockDim.x + threadIdx.x;
    if (i < N_NODES) {
        outn[i] = rsqrtf(fmaxf((float)outc[i], 1.0f));
        inn[i]  = rsqrtf(fmaxf((float)inc[i], 1.0f));
    }
}

// ---------------- hierarchical exclusive scan (3 kernels) ----------------
__global__ __launch_bounds__(256) void scan1(const int* __restrict__ cnt,
                                             int* __restrict__ row_start,
                                             int* __restrict__ bsum, int n) {
    __shared__ int t[256];
    int tid = threadIdx.x;
    int i = blockIdx.x * 256 + tid;
    int v = (i < n) ? cnt[i] : 0;
    t[tid] = v;
    __syncthreads();
#pragma unroll
    for (int off = 1; off < 256; off <<= 1) {
        int x = (tid >= off) ? t[tid - off] : 0;
        __syncthreads();
        t[tid] += x;
        __syncthreads();
    }
    if (i < n) row_start[i] = t[tid] - v;
    if (tid == 255) bsum[blockIdx.x] = t[255];
}

__global__ __launch_bounds__(256) void scan2(int* __restrict__ bsum,
                                             int* __restrict__ boff,
                                             int* __restrict__ row_start, int nb) {
    __shared__ int t[256];
    int tid = threadIdx.x;
    int v = (tid < nb) ? bsum[tid] : 0;
    t[tid] = v;
    __syncthreads();
#pragma unroll
    for (int off = 1; off < 256; off <<= 1) {
        int x = (tid >= off) ? t[tid - off] : 0;
        __syncthreads();
        t[tid] += x;
        __syncthreads();
    }
    if (tid < nb) boff[tid] = t[tid] - v;
    if (tid == 0) row_start[N_NODES] = N_EDGES;
}

__global__ __launch_bounds__(256) void scan3(int* __restrict__ row_start,
                                             const int* __restrict__ boff, int n) {
    int i = blockIdx.x * 256 + threadIdx.x;
    if (i < n) row_start[i] += boff[blockIdx.x];
}

// ---------------- CSR fill ----------------
__global__ void fill_kernel(const int* __restrict__ src, const int* __restrict__ dst,
                            const int* __restrict__ row_start, int* __restrict__ cursor,
                            int* __restrict__ csr_src) {
    int e = blockIdx.x * blockDim.x + threadIdx.x;
    if (e < N_EDGES) {
        int d = dst[e];
        int pos = atomicAdd(&cursor[d], 1);
        csr_src[row_start[d] + pos] = src[e];
    }
}

// ---------------- degree counting sort: hist / scan / scatter ----------------
__global__ void bucket_hist(const int* __restrict__ inc, int* __restrict__ bcnt) {
    int i = blockIdx.x * blockDim.x + threadIdx.x;
    if (i < N_NODES) atomicAdd(&bcnt[min(inc[i], 1023)], 1);
}

__global__ __launch_bounds__(1024) void bucket_scan(const int* __restrict__ bcnt,
                                                    int* __restrict__ boff2) {
    __shared__ int t[1024];
    int tid = threadIdx.x;
    int v = bcnt[tid];
    t[tid] = v;
    __syncthreads();
#pragma unroll
    for (int off = 1; off < 1024; off <<= 1) {
        int x = (tid >= off) ? t[tid - off] : 0;
        __syncthreads();
        t[tid] += x;
        __syncthreads();
    }
    boff2[tid] = t[tid] - v;
}

// pmeta[p] = {node, row_start[node], degree, 0} in degree-sorted order
__global__ void bucket_scatter(const int* __restrict__ inc, const int* __restrict__ row_start,
                               int* __restrict__ bcur, i32x4* __restrict__ pmeta) {
    int i = blockIdx.x * blockDim.x + threadIdx.x;
    if (i < N_NODES) {
        int deg = inc[i];
        int p = atomicAdd(&bcur[min(deg, 1023)], 1);
        i32x4 m;
        m.x = i; m.y = row_start[i]; m.z = deg; m.w = 0;
        pmeta[p] = m;
    }
}

// ---------------- W [K,N] fp32 -> Wt [N,K] fp16 (transpose) ----------------
__global__ __launch_bounds__(256) void conv_W(const float* __restrict__ W,
                                              unsigned short* __restrict__ Wt,
                                              int K, int N) {
    __shared__ float t[32][33];
    int tx = threadIdx.x & 31, ty = threadIdx.x >> 5;   // 32 x 8
    int kb = blockIdx.x * 32, nb = blockIdx.y * 32;
#pragma unroll
    for (int i = 0; i < 4; ++i)
        t[ty + 8 * i][tx] = W[(size_t)(kb + ty + 8 * i) * N + nb + tx];
    __syncthreads();
#pragma unroll
    for (int i = 0; i < 4; ++i) {
        float v = t[tx][ty + 8 * i];
        int n = nb + ty + 8 * i, k = kb + tx;
        Wt[(size_t)n * K + k] = f2h(v);
    }
}

// ---------------- feat [M,512] fp32 -> (outn[row]*feat) fp16 ----------------
__global__ void conv_A(const float4* __restrict__ feat4, const float* __restrict__ outn,
                       ushort4* __restrict__ Af, long total4) {
    long i = (long)blockIdx.x * blockDim.x + threadIdx.x;
    if (i >= total4) return;
    int row = (int)(i >> 7);            // 512/4 = 128 float4 per row
    float s = outn[row];
    float4 v = feat4[i];
    ushort4 h;
    h.x = f2h(v.x * s);
    h.y = f2h(v.y * s);
    h.z = f2h(v.z * s);
    h.w = f2h(v.w * s);
    Af[i] = h;
}

// ---------------- MFMA GEMM: C = A @ B^T, fp16 in/out, fp32 acc, K=512 ----------------
// 128x128 tile, BK=32, 256 threads = 4 waves; global_load_lds (16B) staging.
// Output C is written in CHUNK-BLOCKED layout: C[((col>>5)*M + row)*32 + (col&31)].
__global__ __launch_bounds__(256) void gemm_mfma(
    const unsigned short* __restrict__ A, const unsigned short* __restrict__ B,
    unsigned short* __restrict__ C, int M, int N)
{
    const int K = 512;
    __shared__ unsigned short sA[128 * 32];
    __shared__ unsigned short sB[128 * 32];

    const int tid = threadIdx.x;
    const int rowBase = blockIdx.x * 128;
    const int colBase = blockIdx.y * 128;
    const int wave = tid >> 6;
    const int lane = tid & 63;
    const int wr = (wave >> 1) * 64;
    const int wc = (wave & 1) * 64;
    const int lrow = lane & 15;
    const int quad = lane >> 4;

    f32x4 acc[4][4] = {};

    // staging: thread tid -> row tid>>2 (and +64), k-chunk (tid&3)*8; LDS dest = tid*16 B
    const int crow = tid >> 2;
    const int ck   = (tid & 3) * 8;
    const int ar0 = min(rowBase + crow, M - 1);
    const int ar1 = min(rowBase + 64 + crow, M - 1);
    const int bn0 = colBase + crow;
    const int bn1 = colBase + 64 + crow;
    const int ldsOf0 = tid * 8;          // ushort units
    const int ldsOf1 = 64 * 32 + tid * 8;

    for (int k0 = 0; k0 < K; k0 += 32) {
        __syncthreads();   // previous tile's compute done before overwrite
        async16(sA + ldsOf0, A + (size_t)ar0 * K + k0 + ck);
        async16(sA + ldsOf1, A + (size_t)ar1 * K + k0 + ck);
        async16(sB + ldsOf0, B + (size_t)bn0 * K + k0 + ck);
        async16(sB + ldsOf1, B + (size_t)bn1 * K + k0 + ck);
        __syncthreads();   // drains vmcnt (global_load_lds) + barrier

        half8 av[4], bv[4];
#pragma unroll
        for (int mt = 0; mt < 4; ++mt)
            av[mt] = *(const half8*)&sA[(wr + mt * 16 + lrow) * 32 + quad * 8];
#pragma unroll
        for (int nt = 0; nt < 4; ++nt)
            bv[nt] = *(const half8*)&sB[(wc + nt * 16 + lrow) * 32 + quad * 8];
#pragma unroll
        for (int mt = 0; mt < 4; ++mt)
#pragma unroll
            for (int nt = 0; nt < 4; ++nt)
                acc[mt][nt] = __builtin_amdgcn_mfma_f32_16x16x32_f16(av[mt], bv[nt], acc[mt][nt], 0, 0, 0);
    }

    // epilogue: C/D layout col=lane&15, row=quad*4+reg; store fp16, chunk-blocked.
#pragma unroll
    for (int mt = 0; mt < 4; ++mt) {
        int grow0 = rowBase + wr + mt * 16 + quad * 4;
#pragma unroll
        for (int nt = 0; nt < 4; ++nt) {
            int gcol = colBase + wc + nt * 16 + lrow;
            size_t chunkBase = (size_t)(gcol >> 5) * M * 32 + (gcol & 31);
#pragma unroll
            for (int r = 0; r < 4; ++r) {
                int grow = grow0 + r;
                if (grow < M) C[chunkBase + (size_t)grow * 32] = f2h(acc[mt][nt][r]);
            }
        }
    }
}

// ---------------- chunked gather-aggregate v3 (node-slot, degree-sorted) ----------------
// grid (8, 782, phases). chunk c = z*8+x -> XCD x. Block = 4 waves; wave owns 16
// nodes (sorted by degree via pmeta). Lane = (s = node slot 0..15, f = 0..3).
// Per k-iter: each slot consumes one edge; lane loads 16B of the 64B row; acc
// is per-lane (8 f32) -> NO cross-lane reduction. Indices staged to per-wave
// LDS slab (stride 68: 16B-aligned, <=2-way banks). No __syncthreads at all.
#define KB 64

__global__ __launch_bounds__(256) void agg_f16_v3(
    const unsigned short* __restrict__ H, const int* __restrict__ csr_src,
    const i32x4* __restrict__ pmeta, const float* __restrict__ inn,
    const float* __restrict__ outn, const float* __restrict__ bias,
    unsigned short* __restrict__ Af)
{
    __shared__ int sIdx[4][16][68];
    const int tid = threadIdx.x, lane = tid & 63, w = tid >> 6;
    const int s = lane >> 2, f = lane & 3;
    const int c = blockIdx.z * 8 + blockIdx.x;
    const int t = blockIdx.y * 64 + w * 16 + s;

    int d = 0, st = 0, deg = 0;
    if (t < N_NODES) {
        i32x4 m = __builtin_nontemporal_load(pmeta + t);
        d = m.x; st = m.y; deg = m.z;
    }
    int wmax = deg;
    wmax = max(wmax, __shfl_xor(wmax, 4));
    wmax = max(wmax, __shfl_xor(wmax, 8));
    wmax = max(wmax, __shfl_xor(wmax, 16));
    wmax = max(wmax, __shfl_xor(wmax, 32));

    const unsigned short* Hc = H + (size_t)c * (N_NODES * 32);
    int* slab = &sIdx[w][s][0];
    float a[8] = {};

    for (int kb = 0; kb < wmax; kb += KB) {
        const int kend = min(deg - kb, KB);          // can be <= 0
        const int klim = min(wmax - kb, KB);         // wave-uniform
        // stage this batch's indices: lane covers k == f (mod 4)
        for (int i = f; i < kend; i += 4)
            slab[i] = __builtin_nontemporal_load(csr_src + st + kb + i);
        asm volatile("s_waitcnt lgkmcnt(0)" ::: "memory");  // writes visible cross-lane
        for (int k = 0; k < klim; ++k) {
            int idx = slab[k];                       // broadcast x4, <=2-way banks
            if (k < kend) {
                const ushort8 u = *(const ushort8*)(Hc + (unsigned)idx * 32u + (unsigned)f * 8u);
#pragma unroll
                for (int q = 0; q < 8; ++q) a[q] += h2f(u[q]);
            }
        }
        asm volatile("" ::: "memory");               // keep reads before next overwrite
    }

    if (t < N_NODES) {
        float si = inn[d], so = outn[d];
        float b8[8];
        *(float4*)&b8[0] = *(const float4*)(bias + c * 32 + f * 8);
        *(float4*)&b8[4] = *(const float4*)(bias + c * 32 + f * 8 + 4);
        ushort8 h;
#pragma unroll
        for (int q = 0; q < 8; ++q)
            h[q] = f2h(fmaxf(a[q] * si + b8[q], 0.f) * so);
        __builtin_nontemporal_store(h,
            (ushort8*)(Af + (size_t)d * 512 + c * 32 + f * 8));
    }
}

// ---------------- final chunked aggregate v3: fp32 out, no relu ----------------
__global__ __launch_bounds__(256) void agg_f32_v3(
    const unsigned short* __restrict__ H, const int* __restrict__ csr_src,
    const i32x4* __restrict__ pmeta, const float* __restrict__ inn,
    const float* __restrict__ bias, float* __restrict__ out)
{
    __shared__ int sIdx[4][16][68];
    const int tid = threadIdx.x, lane = tid & 63, w = tid >> 6;
    const int s = lane >> 2, f = lane & 3;
    const int c = blockIdx.x;                        // chunk 0..7
    const int t = blockIdx.y * 64 + w * 16 + s;

    int d = 0, st = 0, deg = 0;
    if (t < N_NODES) {
        i32x4 m = __builtin_nontemporal_load(pmeta + t);
        d = m.x; st = m.y; deg = m.z;
    }
    int wmax = deg;
    wmax = max(wmax, __shfl_xor(wmax, 4));
    wmax = max(wmax, __shfl_xor(wmax, 8));
    wmax = max(wmax, __shfl_xor(wmax, 16));
    wmax = max(wmax, __shfl_xor(wmax, 32));

    const unsigned short* Hc = H + (size_t)c * (N_NODES * 32);
    int* slab = &sIdx[w][s][0];
    float a[8] = {};

    for (int kb = 0; kb < wmax; kb += KB) {
        const int kend = min(deg - kb, KB);
        const int klim = min(wmax - kb, KB);
        for (int i = f; i < kend; i += 4)
            slab[i] = __builtin_nontemporal_load(csr_src + st + kb + i);
        asm volatile("s_waitcnt lgkmcnt(0)" ::: "memory");
        for (int k = 0; k < klim; ++k) {
            int idx = slab[k];
            if (k < kend) {
                const ushort8 u = *(const ushort8*)(Hc + (unsigned)idx * 32u + (unsigned)f * 8u);
#pragma unroll
                for (int q = 0; q < 8; ++q) a[q] += h2f(u[q]);
            }
        }
        asm volatile("" ::: "memory");
    }

    if (t < N_NODES) {
        float si = inn[d];
        float b8[8];
        *(float4*)&b8[0] = *(const float4*)(bias + c * 32 + f * 8);
        *(float4*)&b8[4] = *(const float4*)(bias + c * 32 + f * 8 + 4);
        f32x4 r0, r1;
        r0.x = a[0] * si + b8[0]; r0.y = a[1] * si + b8[1];
        r0.z = a[2] * si + b8[2]; r0.w = a[3] * si + b8[3];
        r1.x = a[4] * si + b8[4]; r1.y = a[5] * si + b8[5];
        r1.z = a[6] * si + b8[6]; r1.w = a[7] * si + b8[7];
        float* op = out + (size_t)d * 256 + c * 32 + f * 8;
        __builtin_nontemporal_store(r0, (f32x4*)op);
        __builtin_nontemporal_store(r1, (f32x4*)(op + 4));
    }
}

extern "C" void kernel_launch(void* const* d_in, const int* in_sizes, int n_in,
                              void* d_out, int out_size, void* d_ws, size_t ws_size,
                              hipStream_t stream) {
    const float* feat = (const float*)d_in[0];
    const int*   src  = (const int*)d_in[1];
    const int*   dst  = (const int*)d_in[2];
    const float* W0   = (const float*)d_in[3];
    const float* b0   = (const float*)d_in[4];
    const float* W1   = (const float*)d_in[5];
    const float* b1   = (const float*)d_in[6];
    const float* W2   = (const float*)d_in[7];
    const float* b2   = (const float*)d_in[8];
    float* out = (float*)d_out;

    // ---- workspace bump allocator (64B aligned) ----
    char* p = (char*)d_ws;
    auto alloc = [&](size_t bytes) {
        char* r = p;
        p += (bytes + 63) & ~(size_t)63;
        return r;
    };
    float* outn = (float*)alloc(N_NODES * 4);
    float* inn  = (float*)alloc(N_NODES * 4);
    int* outc      = (int*)alloc(N_NODES * 4);     // | contiguous zero block:
    int* inc       = (int*)alloc(N_NODES * 4);     // | outc, inc, cursor, bcnt
    int* cursor    = (int*)alloc(N_NODES * 4);     // |
    int* bcnt      = (int*)alloc(1024 * 4);        // |
    int* row_start = (int*)alloc((N_NODES + 1) * 4);
    int* bsum      = (int*)alloc(256 * 4);
    int* boff      = (int*)alloc(256 * 4);
    int* boff2     = (int*)alloc(1024 * 4);
    int* csr_src   = (int*)alloc(N_EDGES * 4);
    i32x4* pmeta   = (i32x4*)alloc((size_t)(N_NODES + 64) * 16);
    unsigned short* W0t = (unsigned short*)alloc(512 * 512 * 2);
    unsigned short* W1t = (unsigned short*)alloc(512 * 512 * 2);
    unsigned short* W2t = (unsigned short*)alloc(256 * 512 * 2);
    unsigned short* Af  = (unsigned short*)alloc((size_t)N_NODES * 512 * 2);
    unsigned short* H   = (unsigned short*)alloc((size_t)N_NODES * 512 * 2);

    const int NB = (N_NODES + 255) / 256;   // 196

    // ---- degrees + norms + CSR + degree sort ----
    hipMemsetAsync(outc, 0, (size_t)3 * N_NODES * 4 + 1024 * 4, stream);
    hist_kernel<<<(N_EDGES + 255) / 256, 256, 0, stream>>>(src, dst, outc, inc);
    norm_kernel<<<(N_NODES + 255) / 256, 256, 0, stream>>>(outc, inc, outn, inn);
    scan1<<<NB, 256, 0, stream>>>(inc, row_start, bsum, N_NODES);
    scan2<<<1, 256, 0, stream>>>(bsum, boff, row_start, NB);
    scan3<<<NB, 256, 0, stream>>>(row_start, boff, N_NODES);
    fill_kernel<<<(N_EDGES + 255) / 256, 256, 0, stream>>>(src, dst, row_start, cursor, csr_src);
    bucket_hist<<<NB, 256, 0, stream>>>(inc, bcnt);
    bucket_scan<<<1, 1024, 0, stream>>>(bcnt, boff2);
    bucket_scatter<<<NB, 256, 0, stream>>>(inc, row_start, boff2, pmeta);

    // ---- weight transpose to fp16 ----
    conv_W<<<dim3(16, 16), 256, 0, stream>>>(W0, W0t, 512, 512);
    conv_W<<<dim3(16, 16), 256, 0, stream>>>(W1, W1t, 512, 512);
    conv_W<<<dim3(16, 8),  256, 0, stream>>>(W2, W2t, 512, 256);

    // ---- feature scale to fp16 ----
    long total4 = (long)N_NODES * 128;
    conv_A<<<(int)((total4 + 255) / 256), 256, 0, stream>>>(
        (const float4*)feat, outn, (ushort4*)Af, total4);

    dim3 g512((N_NODES + 127) / 128, 4);
    dim3 g256((N_NODES + 127) / 128, 2);
    const int NTB = (N_NODES + 63) / 64;    // 782 node tiles (64 nodes/block)
    dim3 gAgg512(8, NTB, 2);                // 16 chunks: xcd = chunk%8, 2 phases
    dim3 gAgg256(8, NTB, 1);                // 8 chunks: one per XCD

    // ---- layer 0 ----
    gemm_mfma<<<g512, 256, 0, stream>>>(Af, W0t, H, N_NODES, 512);
    agg_f16_v3<<<gAgg512, 256, 0, stream>>>(
        H, csr_src, pmeta, inn, outn, b0, Af);

    // ---- layer 1 ----
    gemm_mfma<<<g512, 256, 0, stream>>>(Af, W1t, H, N_NODES, 512);
    agg_f16_v3<<<gAgg512, 256, 0, stream>>>(
        H, csr_src, pmeta, inn, outn, b1, Af);

    // ---- layer 2 (256 out, no relu, fp32) ----
    gemm_mfma<<<g256, 256, 0, stream>>>(Af, W2t, H, N_NODES, 256);
    agg_f32_v3<<<gAgg256, 256, 0, stream>>>(
        H, csr_src, pmeta, inn, b2, out);
}

// Round 5
// 958.997 us; speedup vs baseline: 1.1114x; 1.1114x over previous
//
#include <hip/hip_runtime.h>

#define N_NODES 50000
#define N_EDGES 800000
// feats: 512 -> 512 -> 512 -> 256; K always 512. Internal dtype: fp16.
// H (GEMM output / agg input) is CHUNK-BLOCKED: [chunk][node][32feats]; one
// chunk = 3.2MB < 4MiB per-XCD L2; agg grid pins chunk->XCD via blockIdx.x
// (gridDim.x=8) so random gathers are L2-resident (proven: FETCH 425->56MB).
// v4 agg: CSR is PERMUTED into degree-sorted node order (csr2/prow/porder),
// so each wave's 16 nodes own a contiguous edge range -> coalesced per-wave
// LDS slab staging (v2's proven pattern, wave-private, no barriers) + v3's
// zero-shuffle node-slot gather (slot = 4 lanes x 16B, per-lane accum).

typedef __attribute__((ext_vector_type(8))) _Float16 half8;
typedef __attribute__((ext_vector_type(4))) float f32x4;
typedef __attribute__((ext_vector_type(8))) unsigned short ushort8;

// ---------------- fp16 helpers ----------------
static __device__ __forceinline__ unsigned short f2h(float f) {
    _Float16 h = (_Float16)f;   // RNE
    return __builtin_bit_cast(unsigned short, h);
}
static __device__ __forceinline__ float h2f(unsigned short u) {
    return (float)__builtin_bit_cast(_Float16, u);
}

// async global->LDS, 16B per lane (wave-uniform LDS base + lane*16 layout)
static __device__ __forceinline__ void async16(unsigned short* lds, const unsigned short* g) {
    __builtin_amdgcn_global_load_lds(
        (const __attribute__((address_space(1))) void*)g,
        (__attribute__((address_space(3))) void*)lds, 16, 0, 0);
}

// ---------------- int degree histograms ----------------
__global__ void hist_kernel(const int* __restrict__ src, const int* __restrict__ dst,
                            int* __restrict__ outc, int* __restrict__ inc) {
    int i = blockIdx.x * blockDim.x + threadIdx.x;
    if (i < N_EDGES) {
        atomicAdd(&outc[src[i]], 1);
        atomicAdd(&inc[dst[i]], 1);
    }
}

__global__ void norm_kernel(const int* __restrict__ outc, const int* __restrict__ inc,
                            float* __restrict__ outn, float* __restrict__ inn) {
    int i = blockIdx.x * blockDim.x + threadIdx.x;
    if (i < N_NODES) {
        outn[i] = rsqrtf(fmaxf((float)outc[i], 1.0f));
        inn[i]  = rsqrtf(fmaxf((float)inc[i], 1.0f));
    }
}

// ---------------- hierarchical exclusive scan (3 kernels) ----------------
__global__ __launch_bounds__(256) void scan1(const int* __restrict__ cnt,
                                             int* __restrict__ row_start,
                                             int* __restrict__ bsum, int n) {
    __shared__ int t[256];
    int tid = threadIdx.x;
    int i = blockIdx.x * 256 + tid;
    int v = (i < n) ? cnt[i] : 0;
    t[tid] = v;
    __syncthreads();
#pragma unroll
    for (int off = 1; off < 256; off <<= 1) {
        int x = (tid >= off) ? t[tid - off] : 0;
        __syncthreads();
        t[tid] += x;
        __syncthreads();
    }
    if (i < n) row_start[i] = t[tid] - v;
    if (tid == 255) bsum[blockIdx.x] = t[255];
}

__global__ __launch_bounds__(256) void scan2(int* __restrict__ bsum,
                                             int* __restrict__ boff,
                                             int* __restrict__ row_start, int nb) {
    __shared__ int t[256];
    int tid = threadIdx.x;
    int v = (tid < nb) ? bsum[tid] : 0;
    t[tid] = v;
    __syncthreads();
#pragma unroll
    for (int off = 1; off < 256; off <<= 1) {
        int x = (tid >= off) ? t[tid - off] : 0;
        __syncthreads();
        t[tid] += x;
        __syncthreads();
    }
    if (tid < nb) boff[tid] = t[tid] - v;
    if (tid == 0) row_start[N_NODES] = N_EDGES;
}

__global__ __launch_bounds__(256) void scan3(int* __restrict__ row_start,
                                             const int* __restrict__ boff, int n) {
    int i = blockIdx.x * 256 + threadIdx.x;
    if (i < n) row_start[i] += boff[blockIdx.x];
}

// ---------------- degree counting sort: hist / scan / scatter ----------------
__global__ void bucket_hist(const int* __restrict__ inc, int* __restrict__ bcnt) {
    int i = blockIdx.x * blockDim.x + threadIdx.x;
    if (i < N_NODES) atomicAdd(&bcnt[min(inc[i], 1023)], 1);
}

__global__ __launch_bounds__(1024) void bucket_scan(const int* __restrict__ bcnt,
                                                    int* __restrict__ boff2) {
    __shared__ int t[1024];
    int tid = threadIdx.x;
    int v = bcnt[tid];
    t[tid] = v;
    __syncthreads();
#pragma unroll
    for (int off = 1; off < 1024; off <<= 1) {
        int x = (tid >= off) ? t[tid - off] : 0;
        __syncthreads();
        t[tid] += x;
        __syncthreads();
    }
    boff2[tid] = t[tid] - v;
}

// porder[p]=node, rank[node]=p, pdeg[p]=deg  (degree-sorted order)
__global__ void bucket_scatter(const int* __restrict__ inc, int* __restrict__ bcur,
                               int* __restrict__ porder, int* __restrict__ rank,
                               int* __restrict__ pdeg) {
    int i = blockIdx.x * blockDim.x + threadIdx.x;
    if (i < N_NODES) {
        int deg = inc[i];
        int p = atomicAdd(&bcur[min(deg, 1023)], 1);
        porder[p] = i;
        rank[i] = p;
        pdeg[p] = deg;
    }
}

// ---------------- CSR fill (directly into degree-sorted layout) ----------------
__global__ void fill_kernel(const int* __restrict__ src, const int* __restrict__ dst,
                            const int* __restrict__ rank, const int* __restrict__ prow,
                            int* __restrict__ cursor, int* __restrict__ csr2) {
    int e = blockIdx.x * blockDim.x + threadIdx.x;
    if (e < N_EDGES) {
        int d = dst[e];
        int pos = atomicAdd(&cursor[d], 1);
        csr2[prow[rank[d]] + pos] = src[e];
    }
}

// ---------------- W [K,N] fp32 -> Wt [N,K] fp16 (transpose) ----------------
__global__ __launch_bounds__(256) void conv_W(const float* __restrict__ W,
                                              unsigned short* __restrict__ Wt,
                                              int K, int N) {
    __shared__ float t[32][33];
    int tx = threadIdx.x & 31, ty = threadIdx.x >> 5;   // 32 x 8
    int kb = blockIdx.x * 32, nb = blockIdx.y * 32;
#pragma unroll
    for (int i = 0; i < 4; ++i)
        t[ty + 8 * i][tx] = W[(size_t)(kb + ty + 8 * i) * N + nb + tx];
    __syncthreads();
#pragma unroll
    for (int i = 0; i < 4; ++i) {
        float v = t[tx][ty + 8 * i];
        int n = nb + ty + 8 * i, k = kb + tx;
        Wt[(size_t)n * K + k] = f2h(v);
    }
}

// ---------------- feat [M,512] fp32 -> (outn[row]*feat) fp16 ----------------
__global__ void conv_A(const float4* __restrict__ feat4, const float* __restrict__ outn,
                       ushort4* __restrict__ Af, long total4) {
    long i = (long)blockIdx.x * blockDim.x + threadIdx.x;
    if (i >= total4) return;
    int row = (int)(i >> 7);            // 512/4 = 128 float4 per row
    float s = outn[row];
    float4 v = feat4[i];
    ushort4 h;
    h.x = f2h(v.x * s);
    h.y = f2h(v.y * s);
    h.z = f2h(v.z * s);
    h.w = f2h(v.w * s);
    Af[i] = h;
}

// ---------------- MFMA GEMM: C = A @ B^T, fp16 in/out, fp32 acc, K=512 ----------------
// 128x128 tile, BK=32, 256 threads = 4 waves; global_load_lds (16B) staging.
// Output C is written in CHUNK-BLOCKED layout: C[((col>>5)*M + row)*32 + (col&31)].
__global__ __launch_bounds__(256) void gemm_mfma(
    const unsigned short* __restrict__ A, const unsigned short* __restrict__ B,
    unsigned short* __restrict__ C, int M, int N)
{
    const int K = 512;
    __shared__ unsigned short sA[128 * 32];
    __shared__ unsigned short sB[128 * 32];

    const int tid = threadIdx.x;
    const int rowBase = blockIdx.x * 128;
    const int colBase = blockIdx.y * 128;
    const int wave = tid >> 6;
    const int lane = tid & 63;
    const int wr = (wave >> 1) * 64;
    const int wc = (wave & 1) * 64;
    const int lrow = lane & 15;
    const int quad = lane >> 4;

    f32x4 acc[4][4] = {};

    // staging: thread tid -> row tid>>2 (and +64), k-chunk (tid&3)*8; LDS dest = tid*16 B
    const int crow = tid >> 2;
    const int ck   = (tid & 3) * 8;
    const int ar0 = min(rowBase + crow, M - 1);
    const int ar1 = min(rowBase + 64 + crow, M - 1);
    const int bn0 = colBase + crow;
    const int bn1 = colBase + 64 + crow;
    const int ldsOf0 = tid * 8;          // ushort units
    const int ldsOf1 = 64 * 32 + tid * 8;

    for (int k0 = 0; k0 < K; k0 += 32) {
        __syncthreads();   // previous tile's compute done before overwrite
        async16(sA + ldsOf0, A + (size_t)ar0 * K + k0 + ck);
        async16(sA + ldsOf1, A + (size_t)ar1 * K + k0 + ck);
        async16(sB + ldsOf0, B + (size_t)bn0 * K + k0 + ck);
        async16(sB + ldsOf1, B + (size_t)bn1 * K + k0 + ck);
        __syncthreads();   // drains vmcnt (global_load_lds) + barrier

        half8 av[4], bv[4];
#pragma unroll
        for (int mt = 0; mt < 4; ++mt)
            av[mt] = *(const half8*)&sA[(wr + mt * 16 + lrow) * 32 + quad * 8];
#pragma unroll
        for (int nt = 0; nt < 4; ++nt)
            bv[nt] = *(const half8*)&sB[(wc + nt * 16 + lrow) * 32 + quad * 8];
#pragma unroll
        for (int mt = 0; mt < 4; ++mt)
#pragma unroll
            for (int nt = 0; nt < 4; ++nt)
                acc[mt][nt] = __builtin_amdgcn_mfma_f32_16x16x32_f16(av[mt], bv[nt], acc[mt][nt], 0, 0, 0);
    }

    // epilogue: C/D layout col=lane&15, row=quad*4+reg; store fp16, chunk-blocked.
#pragma unroll
    for (int mt = 0; mt < 4; ++mt) {
        int grow0 = rowBase + wr + mt * 16 + quad * 4;
#pragma unroll
        for (int nt = 0; nt < 4; ++nt) {
            int gcol = colBase + wc + nt * 16 + lrow;
            size_t chunkBase = (size_t)(gcol >> 5) * M * 32 + (gcol & 31);
#pragma unroll
            for (int r = 0; r < 4; ++r) {
                int grow = grow0 + r;
                if (grow < M) C[chunkBase + (size_t)grow * 32] = f2h(acc[mt][nt][r]);
            }
        }
    }
}

// ---------------- chunked gather-aggregate v4 (sorted CSR, wave slab) ----------------
// grid (8, 782, phases). chunk c = z*8+x -> XCD x. Block = 4 waves; wave owns 16
// CONSECUTIVE sorted nodes t0..t0+15 whose edges are CONTIGUOUS in csr2
// [prow[t0], prow[t0+16]). Stage slab coalesced (lane-strided nt loads, wave-
// private, no barriers); lane = (slot s=0..15, f=0..3); slot consumes its own
// subrange; lane gathers 16B of the 64B row; per-lane accum, zero-shuffle.
#define SLAB 1024

__global__ __launch_bounds__(256) void agg_f16_v4(
    const unsigned short* __restrict__ H, const int* __restrict__ csr2,
    const int* __restrict__ porder, const int* __restrict__ prow,
    const float* __restrict__ inn, const float* __restrict__ outn,
    const float* __restrict__ bias, unsigned short* __restrict__ Af)
{
    __shared__ int sIdx[4][SLAB];
    const int tid = threadIdx.x, lane = tid & 63, w = tid >> 6;
    const int s = lane >> 2, f = lane & 3;
    const int c = blockIdx.z * 8 + blockIdx.x;
    const int t = blockIdx.y * 64 + w * 16 + s;

    int d = 0, st = N_EDGES, en = N_EDGES;
    if (t < N_NODES) {
        d  = porder[t];
        st = prow[t];
        en = prow[t + 1];
    }
    const int eStart = __shfl(st, 0);    // slot 0's start (wave-uniform)
    const int eEnd   = __shfl(en, 63);   // slot 15's end

    const unsigned short* Hc = H + (size_t)c * (N_NODES * 32);
    int* slab = sIdx[w];
    float a[8] = {};

    for (int b = eStart; b < eEnd; b += SLAB) {
        const int nstage = min(eEnd - b, SLAB);
        for (int i = lane; i < nstage; i += 64)
            slab[i] = __builtin_nontemporal_load(csr2 + b + i);
        asm volatile("s_waitcnt lgkmcnt(0)" ::: "memory");

        const int js = max(st, b);
        const int je = min(en, b + nstage);
#pragma unroll 4
        for (int k = js; k < je; ++k) {
            int idx = slab[k - b];       // 4-lane broadcast read
            const ushort8 u = *(const ushort8*)(Hc + (unsigned)idx * 32u + (unsigned)f * 8u);
#pragma unroll
            for (int q = 0; q < 8; ++q) a[q] += h2f(u[q]);
        }
        asm volatile("" ::: "memory");   // reads done before next batch overwrites
    }

    if (t < N_NODES) {
        float si = inn[d], so = outn[d];
        float b8[8];
        *(float4*)&b8[0] = *(const float4*)(bias + c * 32 + f * 8);
        *(float4*)&b8[4] = *(const float4*)(bias + c * 32 + f * 8 + 4);
        ushort8 h;
#pragma unroll
        for (int q = 0; q < 8; ++q)
            h[q] = f2h(fmaxf(a[q] * si + b8[q], 0.f) * so);
        __builtin_nontemporal_store(h,
            (ushort8*)(Af + (size_t)d * 512 + c * 32 + f * 8));
    }
}

// ---------------- final chunked aggregate v4: fp32 out, no relu ----------------
__global__ __launch_bounds__(256) void agg_f32_v4(
    const unsigned short* __restrict__ H, const int* __restrict__ csr2,
    const int* __restrict__ porder, const int* __restrict__ prow,
    const float* __restrict__ inn, const float* __restrict__ bias,
    float* __restrict__ out)
{
    __shared__ int sIdx[4][SLAB];
    const int tid = threadIdx.x, lane = tid & 63, w = tid >> 6;
    const int s = lane >> 2, f = lane & 3;
    const int c = blockIdx.x;            // chunk 0..7
    const int t = blockIdx.y * 64 + w * 16 + s;

    int d = 0, st = N_EDGES, en = N_EDGES;
    if (t < N_NODES) {
        d  = porder[t];
        st = prow[t];
        en = prow[t + 1];
    }
    const int eStart = __shfl(st, 0);
    const int eEnd   = __shfl(en, 63);

    const unsigned short* Hc = H + (size_t)c * (N_NODES * 32);
    int* slab = sIdx[w];
    float a[8] = {};

    for (int b = eStart; b < eEnd; b += SLAB) {
        const int nstage = min(eEnd - b, SLAB);
        for (int i = lane; i < nstage; i += 64)
            slab[i] = __builtin_nontemporal_load(csr2 + b + i);
        asm volatile("s_waitcnt lgkmcnt(0)" ::: "memory");

        const int js = max(st, b);
        const int je = min(en, b + nstage);
#pragma unroll 4
        for (int k = js; k < je; ++k) {
            int idx = slab[k - b];
            const ushort8 u = *(const ushort8*)(Hc + (unsigned)idx * 32u + (unsigned)f * 8u);
#pragma unroll
            for (int q = 0; q < 8; ++q) a[q] += h2f(u[q]);
        }
        asm volatile("" ::: "memory");
    }

    if (t < N_NODES) {
        float si = inn[d];
        float b8[8];
        *(float4*)&b8[0] = *(const float4*)(bias + c * 32 + f * 8);
        *(float4*)&b8[4] = *(const float4*)(bias + c * 32 + f * 8 + 4);
        f32x4 r0, r1;
        r0.x = a[0] * si + b8[0]; r0.y = a[1] * si + b8[1];
        r0.z = a[2] * si + b8[2]; r0.w = a[3] * si + b8[3];
        r1.x = a[4] * si + b8[4]; r1.y = a[5] * si + b8[5];
        r1.z = a[6] * si + b8[6]; r1.w = a[7] * si + b8[7];
        float* op = out + (size_t)d * 256 + c * 32 + f * 8;
        __builtin_nontemporal_store(r0, (f32x4*)op);
        __builtin_nontemporal_store(r1, (f32x4*)(op + 4));
    }
}

extern "C" void kernel_launch(void* const* d_in, const int* in_sizes, int n_in,
                              void* d_out, int out_size, void* d_ws, size_t ws_size,
                              hipStream_t stream) {
    const float* feat = (const float*)d_in[0];
    const int*   src  = (const int*)d_in[1];
    const int*   dst  = (const int*)d_in[2];
    const float* W0   = (const float*)d_in[3];
    const float* b0   = (const float*)d_in[4];
    const float* W1   = (const float*)d_in[5];
    const float* b1   = (const float*)d_in[6];
    const float* W2   = (const float*)d_in[7];
    const float* b2   = (const float*)d_in[8];
    float* out = (float*)d_out;

    // ---- workspace bump allocator (64B aligned) ----
    char* p = (char*)d_ws;
    auto alloc = [&](size_t bytes) {
        char* r = p;
        p += (bytes + 63) & ~(size_t)63;
        return r;
    };
    float* outn = (float*)alloc(N_NODES * 4);
    float* inn  = (float*)alloc(N_NODES * 4);
    int* outc      = (int*)alloc(N_NODES * 4);     // | contiguous zero block:
    int* inc       = (int*)alloc(N_NODES * 4);     // | outc, inc, cursor, bcnt
    int* cursor    = (int*)alloc(N_NODES * 4);     // | (N_NODES*4 is 64B-mult)
    int* bcnt      = (int*)alloc(1024 * 4);        // |
    int* porder    = (int*)alloc(N_NODES * 4);
    int* rank      = (int*)alloc(N_NODES * 4);
    int* pdeg      = (int*)alloc(N_NODES * 4);
    int* prow      = (int*)alloc((N_NODES + 1) * 4);
    int* bsum      = (int*)alloc(256 * 4);
    int* boff      = (int*)alloc(256 * 4);
    int* boff2     = (int*)alloc(1024 * 4);
    int* csr2      = (int*)alloc(N_EDGES * 4);
    unsigned short* W0t = (unsigned short*)alloc(512 * 512 * 2);
    unsigned short* W1t = (unsigned short*)alloc(512 * 512 * 2);
    unsigned short* W2t = (unsigned short*)alloc(256 * 512 * 2);
    unsigned short* Af  = (unsigned short*)alloc((size_t)N_NODES * 512 * 2);
    unsigned short* H   = (unsigned short*)alloc((size_t)N_NODES * 512 * 2);

    const int NB = (N_NODES + 255) / 256;   // 196

    // ---- degrees + norms + degree sort + sorted CSR ----
    hipMemsetAsync(outc, 0, (size_t)3 * N_NODES * 4 + 1024 * 4, stream);
    hist_kernel<<<(N_EDGES + 255) / 256, 256, 0, stream>>>(src, dst, outc, inc);
    norm_kernel<<<(N_NODES + 255) / 256, 256, 0, stream>>>(outc, inc, outn, inn);
    bucket_hist<<<NB, 256, 0, stream>>>(inc, bcnt);
    bucket_scan<<<1, 1024, 0, stream>>>(bcnt, boff2);
    bucket_scatter<<<NB, 256, 0, stream>>>(inc, boff2, porder, rank, pdeg);
    scan1<<<NB, 256, 0, stream>>>(pdeg, prow, bsum, N_NODES);
    scan2<<<1, 256, 0, stream>>>(bsum, boff, prow, NB);
    scan3<<<NB, 256, 0, stream>>>(prow, boff, N_NODES);
    fill_kernel<<<(N_EDGES + 255) / 256, 256, 0, stream>>>(src, dst, rank, prow, cursor, csr2);

    // ---- weight transpose to fp16 ----
    conv_W<<<dim3(16, 16), 256, 0, stream>>>(W0, W0t, 512, 512);
    conv_W<<<dim3(16, 16), 256, 0, stream>>>(W1, W1t, 512, 512);
    conv_W<<<dim3(16, 8),  256, 0, stream>>>(W2, W2t, 512, 256);

    // ---- feature scale to fp16 ----
    long total4 = (long)N_NODES * 128;
    conv_A<<<(int)((total4 + 255) / 256), 256, 0, stream>>>(
        (const float4*)feat, outn, (ushort4*)Af, total4);

    dim3 g512((N_NODES + 127) / 128, 4);
    dim3 g256((N_NODES + 127) / 128, 2);
    const int NTB = (N_NODES + 63) / 64;    // 782 node tiles (64 nodes/block)
    dim3 gAgg512(8, NTB, 2);                // 16 chunks: xcd = chunk%8, 2 phases
    dim3 gAgg256(8, NTB, 1);                // 8 chunks: one per XCD

    // ---- layer 0 ----
    gemm_mfma<<<g512, 256, 0, stream>>>(Af, W0t, H, N_NODES, 512);
    agg_f16_v4<<<gAgg512, 256, 0, stream>>>(
        H, csr2, porder, prow, inn, outn, b0, Af);

    // ---- layer 1 ----
    gemm_mfma<<<g512, 256, 0, stream>>>(Af, W1t, H, N_NODES, 512);
    agg_f16_v4<<<gAgg512, 256, 0, stream>>>(
        H, csr2, porder, prow, inn, outn, b1, Af);

    // ---- layer 2 (256 out, no relu, fp32) ----
    gemm_mfma<<<g256, 256, 0, stream>>>(Af, W2t, H, N_NODES, 256);
    agg_f32_v4<<<gAgg256, 256, 0, stream>>>(
        H, csr2, porder, prow, inn, b2, out);
}

// Round 6
// 725.157 us; speedup vs baseline: 1.4698x; 1.3225x over previous
//
#include <hip/hip_runtime.h>

#define N_NODES 50000
#define N_EDGES 800000
// feats: 512 -> 512 -> 512 -> 256; K always 512. Internal dtype: fp16.
// H (GEMM output / agg input) is CHUNK-BLOCKED: [chunk][node][32feats]; one
// chunk = 3.2MB < 4MiB per-XCD L2; agg grid pins chunk->XCD via blockIdx.x
// (gridDim.x=8) so random gathers are L2-resident (proven: FETCH 425->56MB).
// v4 agg: CSR is PERMUTED into degree-sorted node order (csr2/prow/porder),
// so each wave's 16 nodes own a contiguous edge range -> coalesced per-wave
// LDS slab staging + zero-shuffle node-slot gather (4 lanes x 16B per row).
// v5: bucket_hist/bucket_scatter rewritten with per-block LDS aggregation --
// the Poisson(16) degree distribution put ~50K global atomics on ~40 hot
// addresses (~1250-way contention, 132us serialized). LDS-local hist +
// one global atomic per (block, nonzero bucket) kills the serialization.

typedef __attribute__((ext_vector_type(8))) _Float16 half8;
typedef __attribute__((ext_vector_type(4))) float f32x4;
typedef __attribute__((ext_vector_type(8))) unsigned short ushort8;

// ---------------- fp16 helpers ----------------
static __device__ __forceinline__ unsigned short f2h(float f) {
    _Float16 h = (_Float16)f;   // RNE
    return __builtin_bit_cast(unsigned short, h);
}
static __device__ __forceinline__ float h2f(unsigned short u) {
    return (float)__builtin_bit_cast(_Float16, u);
}

// async global->LDS, 16B per lane (wave-uniform LDS base + lane*16 layout)
static __device__ __forceinline__ void async16(unsigned short* lds, const unsigned short* g) {
    __builtin_amdgcn_global_load_lds(
        (const __attribute__((address_space(1))) void*)g,
        (__attribute__((address_space(3))) void*)lds, 16, 0, 0);
}

// ---------------- int degree histograms ----------------
__global__ void hist_kernel(const int* __restrict__ src, const int* __restrict__ dst,
                            int* __restrict__ outc, int* __restrict__ inc) {
    int i = blockIdx.x * blockDim.x + threadIdx.x;
    if (i < N_EDGES) {
        atomicAdd(&outc[src[i]], 1);
        atomicAdd(&inc[dst[i]], 1);
    }
}

__global__ void norm_kernel(const int* __restrict__ outc, const int* __restrict__ inc,
                            float* __restrict__ outn, float* __restrict__ inn) {
    int i = blockIdx.x * blockDim.x + threadIdx.x;
    if (i < N_NODES) {
        outn[i] = rsqrtf(fmaxf((float)outc[i], 1.0f));
        inn[i]  = rsqrtf(fmaxf((float)inc[i], 1.0f));
    }
}

// ---------------- hierarchical exclusive scan (3 kernels) ----------------
__global__ __launch_bounds__(256) void scan1(const int* __restrict__ cnt,
                                             int* __restrict__ row_start,
                                             int* __restrict__ bsum, int n) {
    __shared__ int t[256];
    int tid = threadIdx.x;
    int i = blockIdx.x * 256 + tid;
    int v = (i < n) ? cnt[i] : 0;
    t[tid] = v;
    __syncthreads();
#pragma unroll
    for (int off = 1; off < 256; off <<= 1) {
        int x = (tid >= off) ? t[tid - off] : 0;
        __syncthreads();
        t[tid] += x;
        __syncthreads();
    }
    if (i < n) row_start[i] = t[tid] - v;
    if (tid == 255) bsum[blockIdx.x] = t[255];
}

__global__ __launch_bounds__(256) void scan2(int* __restrict__ bsum,
                                             int* __restrict__ boff,
                                             int* __restrict__ row_start, int nb) {
    __shared__ int t[256];
    int tid = threadIdx.x;
    int v = (tid < nb) ? bsum[tid] : 0;
    t[tid] = v;
    __syncthreads();
#pragma unroll
    for (int off = 1; off < 256; off <<= 1) {
        int x = (tid >= off) ? t[tid - off] : 0;
        __syncthreads();
        t[tid] += x;
        __syncthreads();
    }
    if (tid < nb) boff[tid] = t[tid] - v;
    if (tid == 0) row_start[N_NODES] = N_EDGES;
}

__global__ __launch_bounds__(256) void scan3(int* __restrict__ row_start,
                                             const int* __restrict__ boff, int n) {
    int i = blockIdx.x * 256 + threadIdx.x;
    if (i < n) row_start[i] += boff[blockIdx.x];
}

// ---------------- degree counting sort (LDS-aggregated) ----------------
__global__ __launch_bounds__(256) void bucket_hist(const int* __restrict__ inc,
                                                   int* __restrict__ bcnt) {
    __shared__ int lh[1024];
    int tid = threadIdx.x;
    for (int b = tid; b < 1024; b += 256) lh[b] = 0;
    __syncthreads();
    int i = blockIdx.x * 256 + tid;
    if (i < N_NODES) atomicAdd(&lh[min(inc[i], 1023)], 1);
    __syncthreads();
    for (int b = tid; b < 1024; b += 256) {
        int v = lh[b];
        if (v) atomicAdd(&bcnt[b], v);
    }
}

__global__ __launch_bounds__(1024) void bucket_scan(const int* __restrict__ bcnt,
                                                    int* __restrict__ boff2) {
    __shared__ int t[1024];
    int tid = threadIdx.x;
    int v = bcnt[tid];
    t[tid] = v;
    __syncthreads();
#pragma unroll
    for (int off = 1; off < 1024; off <<= 1) {
        int x = (tid >= off) ? t[tid - off] : 0;
        __syncthreads();
        t[tid] += x;
        __syncthreads();
    }
    boff2[tid] = t[tid] - v;
}

// porder[p]=node, rank[node]=p, pdeg[p]=deg  (degree-sorted order, stable
// within-bucket order not required). Block-aggregated: LDS atomics give each
// thread its local pos; one global atomic per (block, nonzero bucket).
__global__ __launch_bounds__(256) void bucket_scatter(const int* __restrict__ inc,
                               int* __restrict__ bcur,
                               int* __restrict__ porder, int* __restrict__ rank,
                               int* __restrict__ pdeg) {
    __shared__ int lcnt[1024];
    __shared__ int gbase[1024];
    int tid = threadIdx.x;
    for (int b = tid; b < 1024; b += 256) lcnt[b] = 0;
    __syncthreads();
    int i = blockIdx.x * 256 + tid;
    int deg = 0, bkt = 0, lpos = 0;
    if (i < N_NODES) {
        deg = inc[i];
        bkt = min(deg, 1023);
        lpos = atomicAdd(&lcnt[bkt], 1);
    }
    __syncthreads();
    for (int b = tid; b < 1024; b += 256) {
        int v = lcnt[b];
        if (v) gbase[b] = atomicAdd(&bcur[b], v);
    }
    __syncthreads();
    if (i < N_NODES) {
        int p = gbase[bkt] + lpos;
        porder[p] = i;
        rank[i] = p;
        pdeg[p] = deg;
    }
}

// ---------------- CSR fill (directly into degree-sorted layout) ----------------
__global__ void fill_kernel(const int* __restrict__ src, const int* __restrict__ dst,
                            const int* __restrict__ rank, const int* __restrict__ prow,
                            int* __restrict__ cursor, int* __restrict__ csr2) {
    int e = blockIdx.x * blockDim.x + threadIdx.x;
    if (e < N_EDGES) {
        int d = dst[e];
        int pos = atomicAdd(&cursor[d], 1);
        csr2[prow[rank[d]] + pos] = src[e];
    }
}

// ---------------- W [K,N] fp32 -> Wt [N,K] fp16 (transpose) ----------------
__global__ __launch_bounds__(256) void conv_W(const float* __restrict__ W,
                                              unsigned short* __restrict__ Wt,
                                              int K, int N) {
    __shared__ float t[32][33];
    int tx = threadIdx.x & 31, ty = threadIdx.x >> 5;   // 32 x 8
    int kb = blockIdx.x * 32, nb = blockIdx.y * 32;
#pragma unroll
    for (int i = 0; i < 4; ++i)
        t[ty + 8 * i][tx] = W[(size_t)(kb + ty + 8 * i) * N + nb + tx];
    __syncthreads();
#pragma unroll
    for (int i = 0; i < 4; ++i) {
        float v = t[tx][ty + 8 * i];
        int n = nb + ty + 8 * i, k = kb + tx;
        Wt[(size_t)n * K + k] = f2h(v);
    }
}

// ---------------- feat [M,512] fp32 -> (outn[row]*feat) fp16 ----------------
__global__ void conv_A(const float4* __restrict__ feat4, const float* __restrict__ outn,
                       ushort4* __restrict__ Af, long total4) {
    long i = (long)blockIdx.x * blockDim.x + threadIdx.x;
    if (i >= total4) return;
    int row = (int)(i >> 7);            // 512/4 = 128 float4 per row
    float s = outn[row];
    float4 v = feat4[i];
    ushort4 h;
    h.x = f2h(v.x * s);
    h.y = f2h(v.y * s);
    h.z = f2h(v.z * s);
    h.w = f2h(v.w * s);
    Af[i] = h;
}

// ---------------- MFMA GEMM: C = A @ B^T, fp16 in/out, fp32 acc, K=512 ----------------
// 128x128 tile, BK=32, 256 threads = 4 waves; global_load_lds (16B) staging.
// Output C is written in CHUNK-BLOCKED layout: C[((col>>5)*M + row)*32 + (col&31)].
__global__ __launch_bounds__(256) void gemm_mfma(
    const unsigned short* __restrict__ A, const unsigned short* __restrict__ B,
    unsigned short* __restrict__ C, int M, int N)
{
    const int K = 512;
    __shared__ unsigned short sA[128 * 32];
    __shared__ unsigned short sB[128 * 32];

    const int tid = threadIdx.x;
    const int rowBase = blockIdx.x * 128;
    const int colBase = blockIdx.y * 128;
    const int wave = tid >> 6;
    const int lane = tid & 63;
    const int wr = (wave >> 1) * 64;
    const int wc = (wave & 1) * 64;
    const int lrow = lane & 15;
    const int quad = lane >> 4;

    f32x4 acc[4][4] = {};

    // staging: thread tid -> row tid>>2 (and +64), k-chunk (tid&3)*8; LDS dest = tid*16 B
    const int crow = tid >> 2;
    const int ck   = (tid & 3) * 8;
    const int ar0 = min(rowBase + crow, M - 1);
    const int ar1 = min(rowBase + 64 + crow, M - 1);
    const int bn0 = colBase + crow;
    const int bn1 = colBase + 64 + crow;
    const int ldsOf0 = tid * 8;          // ushort units
    const int ldsOf1 = 64 * 32 + tid * 8;

    for (int k0 = 0; k0 < K; k0 += 32) {
        __syncthreads();   // previous tile's compute done before overwrite
        async16(sA + ldsOf0, A + (size_t)ar0 * K + k0 + ck);
        async16(sA + ldsOf1, A + (size_t)ar1 * K + k0 + ck);
        async16(sB + ldsOf0, B + (size_t)bn0 * K + k0 + ck);
        async16(sB + ldsOf1, B + (size_t)bn1 * K + k0 + ck);
        __syncthreads();   // drains vmcnt (global_load_lds) + barrier

        half8 av[4], bv[4];
#pragma unroll
        for (int mt = 0; mt < 4; ++mt)
            av[mt] = *(const half8*)&sA[(wr + mt * 16 + lrow) * 32 + quad * 8];
#pragma unroll
        for (int nt = 0; nt < 4; ++nt)
            bv[nt] = *(const half8*)&sB[(wc + nt * 16 + lrow) * 32 + quad * 8];
#pragma unroll
        for (int mt = 0; mt < 4; ++mt)
#pragma unroll
            for (int nt = 0; nt < 4; ++nt)
                acc[mt][nt] = __builtin_amdgcn_mfma_f32_16x16x32_f16(av[mt], bv[nt], acc[mt][nt], 0, 0, 0);
    }

    // epilogue: C/D layout col=lane&15, row=quad*4+reg; store fp16, chunk-blocked.
#pragma unroll
    for (int mt = 0; mt < 4; ++mt) {
        int grow0 = rowBase + wr + mt * 16 + quad * 4;
#pragma unroll
        for (int nt = 0; nt < 4; ++nt) {
            int gcol = colBase + wc + nt * 16 + lrow;
            size_t chunkBase = (size_t)(gcol >> 5) * M * 32 + (gcol & 31);
#pragma unroll
            for (int r = 0; r < 4; ++r) {
                int grow = grow0 + r;
                if (grow < M) C[chunkBase + (size_t)grow * 32] = f2h(acc[mt][nt][r]);
            }
        }
    }
}

// ---------------- chunked gather-aggregate v4 (sorted CSR, wave slab) ----------------
// grid (8, 782, phases). chunk c = z*8+x -> XCD x. Block = 4 waves; wave owns 16
// CONSECUTIVE sorted nodes t0..t0+15 whose edges are CONTIGUOUS in csr2
// [prow[t0], prow[t0+16]). Stage slab coalesced (lane-strided nt loads, wave-
// private, no barriers); lane = (slot s=0..15, f=0..3); slot consumes its own
// subrange; lane gathers 16B of the 64B row; per-lane accum, zero-shuffle.
#define SLAB 1024

__global__ __launch_bounds__(256) void agg_f16_v4(
    const unsigned short* __restrict__ H, const int* __restrict__ csr2,
    const int* __restrict__ porder, const int* __restrict__ prow,
    const float* __restrict__ inn, const float* __restrict__ outn,
    const float* __restrict__ bias, unsigned short* __restrict__ Af)
{
    __shared__ int sIdx[4][SLAB];
    const int tid = threadIdx.x, lane = tid & 63, w = tid >> 6;
    const int s = lane >> 2, f = lane & 3;
    const int c = blockIdx.z * 8 + blockIdx.x;
    const int t = blockIdx.y * 64 + w * 16 + s;

    int d = 0, st = N_EDGES, en = N_EDGES;
    if (t < N_NODES) {
        d  = porder[t];
        st = prow[t];
        en = prow[t + 1];
    }
    const int eStart = __shfl(st, 0);    // slot 0's start (wave-uniform)
    const int eEnd   = __shfl(en, 63);   // slot 15's end

    const unsigned short* Hc = H + (size_t)c * (N_NODES * 32);
    int* slab = sIdx[w];
    float a[8] = {};

    for (int b = eStart; b < eEnd; b += SLAB) {
        const int nstage = min(eEnd - b, SLAB);
        for (int i = lane; i < nstage; i += 64)
            slab[i] = __builtin_nontemporal_load(csr2 + b + i);
        asm volatile("s_waitcnt lgkmcnt(0)" ::: "memory");

        const int js = max(st, b);
        const int je = min(en, b + nstage);
#pragma unroll 4
        for (int k = js; k < je; ++k) {
            int idx = slab[k - b];       // 4-lane broadcast read
            const ushort8 u = *(const ushort8*)(Hc + (unsigned)idx * 32u + (unsigned)f * 8u);
#pragma unroll
            for (int q = 0; q < 8; ++q) a[q] += h2f(u[q]);
        }
        asm volatile("" ::: "memory");   // reads done before next batch overwrites
    }

    if (t < N_NODES) {
        float si = inn[d], so = outn[d];
        float b8[8];
        *(float4*)&b8[0] = *(const float4*)(bias + c * 32 + f * 8);
        *(float4*)&b8[4] = *(const float4*)(bias + c * 32 + f * 8 + 4);
        ushort8 h;
#pragma unroll
        for (int q = 0; q < 8; ++q)
            h[q] = f2h(fmaxf(a[q] * si + b8[q], 0.f) * so);
        __builtin_nontemporal_store(h,
            (ushort8*)(Af + (size_t)d * 512 + c * 32 + f * 8));
    }
}

// ---------------- final chunked aggregate v4: fp32 out, no relu ----------------
__global__ __launch_bounds__(256) void agg_f32_v4(
    const unsigned short* __restrict__ H, const int* __restrict__ csr2,
    const int* __restrict__ porder, const int* __restrict__ prow,
    const float* __restrict__ inn, const float* __restrict__ bias,
    float* __restrict__ out)
{
    __shared__ int sIdx[4][SLAB];
    const int tid = threadIdx.x, lane = tid & 63, w = tid >> 6;
    const int s = lane >> 2, f = lane & 3;
    const int c = blockIdx.x;            // chunk 0..7
    const int t = blockIdx.y * 64 + w * 16 + s;

    int d = 0, st = N_EDGES, en = N_EDGES;
    if (t < N_NODES) {
        d  = porder[t];
        st = prow[t];
        en = prow[t + 1];
    }
    const int eStart = __shfl(st, 0);
    const int eEnd   = __shfl(en, 63);

    const unsigned short* Hc = H + (size_t)c * (N_NODES * 32);
    int* slab = sIdx[w];
    float a[8] = {};

    for (int b = eStart; b < eEnd; b += SLAB) {
        const int nstage = min(eEnd - b, SLAB);
        for (int i = lane; i < nstage; i += 64)
            slab[i] = __builtin_nontemporal_load(csr2 + b + i);
        asm volatile("s_waitcnt lgkmcnt(0)" ::: "memory");

        const int js = max(st, b);
        const int je = min(en, b + nstage);
#pragma unroll 4
        for (int k = js; k < je; ++k) {
            int idx = slab[k - b];
            const ushort8 u = *(const ushort8*)(Hc + (unsigned)idx * 32u + (unsigned)f * 8u);
#pragma unroll
            for (int q = 0; q < 8; ++q) a[q] += h2f(u[q]);
        }
        asm volatile("" ::: "memory");
    }

    if (t < N_NODES) {
        float si = inn[d];
        float b8[8];
        *(float4*)&b8[0] = *(const float4*)(bias + c * 32 + f * 8);
        *(float4*)&b8[4] = *(const float4*)(bias + c * 32 + f * 8 + 4);
        f32x4 r0, r1;
        r0.x = a[0] * si + b8[0]; r0.y = a[1] * si + b8[1];
        r0.z = a[2] * si + b8[2]; r0.w = a[3] * si + b8[3];
        r1.x = a[4] * si + b8[4]; r1.y = a[5] * si + b8[5];
        r1.z = a[6] * si + b8[6]; r1.w = a[7] * si + b8[7];
        float* op = out + (size_t)d * 256 + c * 32 + f * 8;
        __builtin_nontemporal_store(r0, (f32x4*)op);
        __builtin_nontemporal_store(r1, (f32x4*)(op + 4));
    }
}

extern "C" void kernel_launch(void* const* d_in, const int* in_sizes, int n_in,
                              void* d_out, int out_size, void* d_ws, size_t ws_size,
                              hipStream_t stream) {
    const float* feat = (const float*)d_in[0];
    const int*   src  = (const int*)d_in[1];
    const int*   dst  = (const int*)d_in[2];
    const float* W0   = (const float*)d_in[3];
    const float* b0   = (const float*)d_in[4];
    const float* W1   = (const float*)d_in[5];
    const float* b1   = (const float*)d_in[6];
    const float* W2   = (const float*)d_in[7];
    const float* b2   = (const float*)d_in[8];
    float* out = (float*)d_out;

    // ---- workspace bump allocator (64B aligned) ----
    char* p = (char*)d_ws;
    auto alloc = [&](size_t bytes) {
        char* r = p;
        p += (bytes + 63) & ~(size_t)63;
        return r;
    };
    float* outn = (float*)alloc(N_NODES * 4);
    float* inn  = (float*)alloc(N_NODES * 4);
    int* outc      = (int*)alloc(N_NODES * 4);     // | contiguous zero block:
    int* inc       = (int*)alloc(N_NODES * 4);     // | outc, inc, cursor, bcnt
    int* cursor    = (int*)alloc(N_NODES * 4);     // | (N_NODES*4 is 64B-mult)
    int* bcnt      = (int*)alloc(1024 * 4);        // |
    int* porder    = (int*)alloc(N_NODES * 4);
    int* rank      = (int*)alloc(N_NODES * 4);
    int* pdeg      = (int*)alloc(N_NODES * 4);
    int* prow      = (int*)alloc((N_NODES + 1) * 4);
    int* bsum      = (int*)alloc(256 * 4);
    int* boff      = (int*)alloc(256 * 4);
    int* boff2     = (int*)alloc(1024 * 4);
    int* csr2      = (int*)alloc(N_EDGES * 4);
    unsigned short* W0t = (unsigned short*)alloc(512 * 512 * 2);
    unsigned short* W1t = (unsigned short*)alloc(512 * 512 * 2);
    unsigned short* W2t = (unsigned short*)alloc(256 * 512 * 2);
    unsigned short* Af  = (unsigned short*)alloc((size_t)N_NODES * 512 * 2);
    unsigned short* H   = (unsigned short*)alloc((size_t)N_NODES * 512 * 2);

    const int NB = (N_NODES + 255) / 256;   // 196

    // ---- degrees + norms + degree sort + sorted CSR ----
    hipMemsetAsync(outc, 0, (size_t)3 * N_NODES * 4 + 1024 * 4, stream);
    hist_kernel<<<(N_EDGES + 255) / 256, 256, 0, stream>>>(src, dst, outc, inc);
    norm_kernel<<<(N_NODES + 255) / 256, 256, 0, stream>>>(outc, inc, outn, inn);
    bucket_hist<<<NB, 256, 0, stream>>>(inc, bcnt);
    bucket_scan<<<1, 1024, 0, stream>>>(bcnt, boff2);
    bucket_scatter<<<NB, 256, 0, stream>>>(inc, boff2, porder, rank, pdeg);
    scan1<<<NB, 256, 0, stream>>>(pdeg, prow, bsum, N_NODES);
    scan2<<<1, 256, 0, stream>>>(bsum, boff, prow, NB);
    scan3<<<NB, 256, 0, stream>>>(prow, boff, N_NODES);
    fill_kernel<<<(N_EDGES + 255) / 256, 256, 0, stream>>>(src, dst, rank, prow, cursor, csr2);

    // ---- weight transpose to fp16 ----
    conv_W<<<dim3(16, 16), 256, 0, stream>>>(W0, W0t, 512, 512);
    conv_W<<<dim3(16, 16), 256, 0, stream>>>(W1, W1t, 512, 512);
    conv_W<<<dim3(16, 8),  256, 0, stream>>>(W2, W2t, 512, 256);

    // ---- feature scale to fp16 ----
    long total4 = (long)N_NODES * 128;
    conv_A<<<(int)((total4 + 255) / 256), 256, 0, stream>>>(
        (const float4*)feat, outn, (ushort4*)Af, total4);

    dim3 g512((N_NODES + 127) / 128, 4);
    dim3 g256((N_NODES + 127) / 128, 2);
    const int NTB = (N_NODES + 63) / 64;    // 782 node tiles (64 nodes/block)
    dim3 gAgg512(8, NTB, 2);                // 16 chunks: xcd = chunk%8, 2 phases
    dim3 gAgg256(8, NTB, 1);                // 8 chunks: one per XCD

    // ---- layer 0 ----
    gemm_mfma<<<g512, 256, 0, stream>>>(Af, W0t, H, N_NODES, 512);
    agg_f16_v4<<<gAgg512, 256, 0, stream>>>(
        H, csr2, porder, prow, inn, outn, b0, Af);

    // ---- layer 1 ----
    gemm_mfma<<<g512, 256, 0, stream>>>(Af, W1t, H, N_NODES, 512);
    agg_f16_v4<<<gAgg512, 256, 0, stream>>>(
        H, csr2, porder, prow, inn, outn, b1, Af);

    // ---- layer 2 (256 out, no relu, fp32) ----
    gemm_mfma<<<g256, 256, 0, stream>>>(Af, W2t, H, N_NODES, 256);
    agg_f32_v4<<<gAgg256, 256, 0, stream>>>(
        H, csr2, porder, prow, inn, b2, out);
}